// Round 17
// baseline (523.719 us; speedup 1.0000x reference)
//
#include <hip/hip_runtime.h>

#define NN 4096
#define DM 1024
#define MD 8
#define NW 256          // worker blocks = column slices
#define NCOL 4          // columns per block (NW*NCOL = DM)
#define NT 512          // threads per k_levels block
#define NWAVE (NT / 64)
#define UR 4            // B-phase row unroll per wave (UR=8 spills at NT=512 — R15)
#define MAXL 4097

// meta layout (int offsets within meta region of d_ws)
#define MI_NLEV 0
#define MI_ROOTPOS 1
#define MI_BWFLAG 2     // backward-liveness done flag (block1 -> block0)
#define MI_ARRIVE 8     // arrive[NW]
#define MI_LO 1024      // levelOffset[nL+1]
#define MI_NL 6144      // live count per level
#define MI_PERM 10240   // perm[4096] (row -> node)
#define MI_DCNT 14336   // dep count per permuted row
#define MI_INV 18432    // (float) 1/nd per permuted row
#define MI_DPOS 22528   // dpos[4096*8]: permuted dep rows (ends at 55296)
#define MI_LIV 55296    // liv[4096] scratch (block1 -> block0)

typedef __attribute__((ext_vector_type(8))) short bf16x8;
typedef __attribute__((ext_vector_type(8))) unsigned short ushort8;
typedef __attribute__((ext_vector_type(4))) float f32x4;

__device__ __forceinline__ float gelu_f(float x) {
  return 0.5f * x * (1.0f + erff(x * 0.70710678118654752440f));
}
__device__ __forceinline__ unsigned short f2bf(float x) {   // RTNE
  unsigned int u = __builtin_bit_cast(unsigned int, x);
  u += 0x7FFFu + ((u >> 16) & 1u);
  return (unsigned short)(u >> 16);
}
__device__ __forceinline__ float bf2f(unsigned short v) {
  return __builtin_bit_cast(float, (unsigned int)v << 16);
}

// ---------------- fused: block 0 = forward levels + sort; block 1 = backward
// ---------------- liveness; blocks 2..257 = preQ MFMA tiles (inline Q cvt) ----------------
__global__ __launch_bounds__(1024) void k_fused(
    const float* __restrict__ Q, const float* __restrict__ W1,
    const float* __restrict__ b1, const int* __restrict__ dep_idx,
    const int* __restrict__ dep_mask, int* __restrict__ meta,
    float* __restrict__ preQ) {
  __shared__ int lvl[NN];      // 16KB (block 0)
  __shared__ int livS[NN];     // 16KB (block 1: liveness; block 0: liv copy)
  __shared__ int cnt[2048];    // 8KB  (nL << 1024)
  __shared__ int pos[NN];      // 16KB
  __shared__ int wflag[2][16];
  __shared__ int s_max;
  const int t = threadIdx.x;
  const int wid = t >> 6;

  if (blockIdx.x >= 2) {
    // ---- preq tile: 128x128 MFMA, inline fp32->bf16 for Q and W1 ----
    if (t >= 256) return;
    const int bid = blockIdx.x - 2;
    const int wave = t >> 6, lane = t & 63;
    const int wm = wave >> 1, wn = wave & 1;
    const int m0 = (bid >> 3) * 128 + wm * 64;
    const int n0 = (bid & 7) * 128 + wn * 64;
    const int lrow = lane & 15;           // A/B row within 16
    const int klo = (lane >> 4) * 8;      // k sub-chunk
    f32x4 acc[4][4] = {};
    for (int k0 = 0; k0 < DM; k0 += 32) {
      bf16x8 af[4];
      #pragma unroll
      for (int f = 0; f < 4; ++f) {
        const float* qsrc = &Q[(size_t)(m0 + f * 16 + lrow) * DM + k0 + klo];
        float4 q0 = *(const float4*)&qsrc[0];
        float4 q1 = *(const float4*)&qsrc[4];
        bf16x8 aa;
        aa[0] = (short)f2bf(q0.x); aa[1] = (short)f2bf(q0.y);
        aa[2] = (short)f2bf(q0.z); aa[3] = (short)f2bf(q0.w);
        aa[4] = (short)f2bf(q1.x); aa[5] = (short)f2bf(q1.y);
        aa[6] = (short)f2bf(q1.z); aa[7] = (short)f2bf(q1.w);
        af[f] = aa;
      }
      bf16x8 bfr[4];
      #pragma unroll
      for (int g = 0; g < 4; ++g) {
        const float* wsrc = &W1[(size_t)(n0 + g * 16 + lrow) * 2048 + k0 + klo];
        float4 w0 = *(const float4*)&wsrc[0];
        float4 w1 = *(const float4*)&wsrc[4];
        bf16x8 bb;
        bb[0] = (short)f2bf(w0.x); bb[1] = (short)f2bf(w0.y);
        bb[2] = (short)f2bf(w0.z); bb[3] = (short)f2bf(w0.w);
        bb[4] = (short)f2bf(w1.x); bb[5] = (short)f2bf(w1.y);
        bb[6] = (short)f2bf(w1.z); bb[7] = (short)f2bf(w1.w);
        bfr[g] = bb;
      }
      #pragma unroll
      for (int f = 0; f < 4; ++f)
        #pragma unroll
        for (int g = 0; g < 4; ++g)
          acc[f][g] = __builtin_amdgcn_mfma_f32_16x16x32_bf16(af[f], bfr[g], acc[f][g], 0, 0, 0);
    }
    float b1v[4];
    #pragma unroll
    for (int g = 0; g < 4; ++g) b1v[g] = b1[n0 + g * 16 + lrow];
    const int mrow = (lane >> 4) * 4;
    #pragma unroll
    for (int f = 0; f < 4; ++f)
      #pragma unroll
      for (int g = 0; g < 4; ++g) {
        const int n = n0 + g * 16 + lrow;
        #pragma unroll
        for (int r = 0; r < 4; ++r)
          preQ[(size_t)(m0 + f * 16 + mrow + r) * DM + n] = acc[f][g][r] + b1v[g];
      }
    return;
  }

  if (blockIdx.x == 1) {
    // ---- backward transitive liveness from root (independent of levels) ----
    for (int i = t; i < NN; i += 1024) livS[i] = (i == NN - 1) ? 1 : 0;
    __syncthreads();
    int par = 0;
    for (int u = 3; u >= 0; --u) {
      const int i = u * 1024 + t;
      const int4 d0 = *(const int4*)&dep_idx[i * MD];
      const int4 d1 = *(const int4*)&dep_idx[i * MD + 4];
      const int4 m0 = *(const int4*)&dep_mask[i * MD];
      const int4 m1 = *(const int4*)&dep_mask[i * MD + 4];
      for (;;) {
        bool ch = false;
        if (livS[i]) {
          if (m0.x && !livS[d0.x]) { livS[d0.x] = 1; ch = true; }
          if (m0.y && !livS[d0.y]) { livS[d0.y] = 1; ch = true; }
          if (m0.z && !livS[d0.z]) { livS[d0.z] = 1; ch = true; }
          if (m0.w && !livS[d0.w]) { livS[d0.w] = 1; ch = true; }
          if (m1.x && !livS[d1.x]) { livS[d1.x] = 1; ch = true; }
          if (m1.y && !livS[d1.y]) { livS[d1.y] = 1; ch = true; }
          if (m1.z && !livS[d1.z]) { livS[d1.z] = 1; ch = true; }
          if (m1.w && !livS[d1.w]) { livS[d1.w] = 1; ch = true; }
        }
        const bool anyw = (__ballot(ch) != 0);
        if ((t & 63) == 0) wflag[par][wid] = anyw ? 1 : 0;
        __syncthreads();
        int any = 0;
        #pragma unroll
        for (int w = 0; w < 16; ++w) any |= wflag[par][w];
        par ^= 1;
        if (!any) break;
      }
    }
    // publish liv + flag (agent-scope write-through; syncthreads drains vmcnt)
    for (int i = t; i < NN; i += 1024)
      __hip_atomic_store(&meta[MI_LIV + i], livS[i], __ATOMIC_RELAXED, __HIP_MEMORY_SCOPE_AGENT);
    __syncthreads();
    if (t == 0)
      __hip_atomic_store(&meta[MI_BWFLAG], 1, __ATOMIC_RELAXED, __HIP_MEMORY_SCOPE_AGENT);
    return;
  }

  // ---- block 0: forward longest-path levels (ballot GS), then sort ----
  for (int i = t; i < NN; i += 1024) lvl[i] = 0;
  for (int i = t; i < 2048; i += 1024) cnt[i] = 0;
  if (t == 0) s_max = 0;
  __syncthreads();

  int par = 0;
  for (int u = 0; u < 4; ++u) {
    const int i = u * 1024 + t;
    const int4 d0 = *(const int4*)&dep_idx[i * MD];
    const int4 d1 = *(const int4*)&dep_idx[i * MD + 4];
    const int4 m0 = *(const int4*)&dep_mask[i * MD];
    const int4 m1 = *(const int4*)&dep_mask[i * MD + 4];
    int my = 0;
    for (;;) {
      int m = 0;
      if (m0.x) { int l = lvl[d0.x] + 1; m = m > l ? m : l; }
      if (m0.y) { int l = lvl[d0.y] + 1; m = m > l ? m : l; }
      if (m0.z) { int l = lvl[d0.z] + 1; m = m > l ? m : l; }
      if (m0.w) { int l = lvl[d0.w] + 1; m = m > l ? m : l; }
      if (m1.x) { int l = lvl[d1.x] + 1; m = m > l ? m : l; }
      if (m1.y) { int l = lvl[d1.y] + 1; m = m > l ? m : l; }
      if (m1.z) { int l = lvl[d1.z] + 1; m = m > l ? m : l; }
      if (m1.w) { int l = lvl[d1.w] + 1; m = m > l ? m : l; }
      bool ch = false;
      if (m > my) { my = m; lvl[i] = m; ch = true; }
      const bool anyw = (__ballot(ch) != 0);
      if ((t & 63) == 0) wflag[par][wid] = anyw ? 1 : 0;
      __syncthreads();
      int any = 0;
      #pragma unroll
      for (int w = 0; w < 16; ++w) any |= wflag[par][w];
      par ^= 1;
      if (!any) break;
    }
  }

  // ---- wait for block 1's liveness, copy to LDS ----
  if (t == 0) {
    while (__hip_atomic_load(&meta[MI_BWFLAG], __ATOMIC_RELAXED, __HIP_MEMORY_SCOPE_AGENT) != 1)
      __builtin_amdgcn_s_sleep(8);
  }
  __syncthreads();
  for (int i = t; i < NN; i += 1024)
    livS[i] = __hip_atomic_load(&meta[MI_LIV + i], __ATOMIC_RELAXED, __HIP_MEMORY_SCOPE_AGENT);
  __syncthreads();

  // ---- counting sort by key = 2*level + (dead?1:0) ----
  for (int i = t; i < NN; i += 1024) {
    atomicAdd(&cnt[2 * lvl[i] + (livS[i] ? 0 : 1)], 1);
    atomicMax(&s_max, lvl[i]);
  }
  __syncthreads();
  const int nL = s_max + 1;
  if (t == 0) {
    int off = 0;
    for (int l = 0; l < nL; ++l) {
      meta[MI_LO + l] = off;
      meta[MI_NL + l] = cnt[2 * l];
      const int a = cnt[2 * l], b = cnt[2 * l + 1];
      cnt[2 * l] = off; off += a;
      cnt[2 * l + 1] = off; off += b;
    }
    meta[MI_LO + nL] = off;
    meta[MI_NLEV] = nL;
  }
  __syncthreads();
  for (int i = t; i < NN; i += 1024)
    pos[i] = atomicAdd(&cnt[2 * lvl[i] + (livS[i] ? 0 : 1)], 1);
  __syncthreads();
  for (int i = t; i < NN; i += 1024) {
    const int r = pos[i];
    meta[MI_PERM + r] = i;
    const int4 d0 = *(const int4*)&dep_idx[i * MD];
    const int4 d1 = *(const int4*)&dep_idx[i * MD + 4];
    const int4 m0 = *(const int4*)&dep_mask[i * MD];
    const int4 m1 = *(const int4*)&dep_mask[i * MD + 4];
    const int dd[8] = {d0.x, d0.y, d0.z, d0.w, d1.x, d1.y, d1.z, d1.w};
    const int mm[8] = {m0.x, m0.y, m0.z, m0.w, m1.x, m1.y, m1.z, m1.w};
    int nd = 0;
    #pragma unroll
    for (int k = 0; k < MD; ++k)
      if (mm[k]) { meta[MI_DPOS + r * MD + nd] = pos[dd[k]]; ++nd; }
    for (int k = nd; k < MD; ++k) meta[MI_DPOS + r * MD + k] = 0;
    meta[MI_DCNT + r] = nd;
    ((float*)meta)[MI_INV + r] = nd ? 1.0f / (float)nd : 0.0f;
  }
  if (t == 0) meta[MI_ROOTPOS] = pos[NN - 1];
  for (int i = t; i < NW; i += 1024) meta[MI_ARRIVE + i] = 0;
}

// ---------------- persistent column-sliced dataflow (bf16 h, W in VGPRs) + logits ----------------
__global__ __launch_bounds__(NT) void k_levels(
    const float* __restrict__ W1, const float* __restrict__ preQ,
    unsigned short* __restrict__ hPb, float4* __restrict__ gPan, int* __restrict__ meta,
    const float* __restrict__ W2, const float* __restrict__ b2, float* __restrict__ out) {
  const int tid = threadIdx.x;
  const int wb = blockIdx.x;
  const int c0 = wb * NCOL;
  const int wave = tid >> 6, lane = tid & 63;
  const int nL = meta[MI_NLEV];
  const int rootRow = meta[MI_ROOTPOS];
  __shared__ int s_lo[MAXL];
  __shared__ int s_nl[MAXL];
  __shared__ float4 preLDS[NT];
  for (int i = tid; i <= nL; i += NT) s_lo[i] = meta[MI_LO + i];
  for (int i = tid; i < nL; i += NT) s_nl[i] = meta[MI_NL + i];
  // W1c slice (4 cols x 1024 k) fp32 in registers; lane's k-window = lane*16..+15
  float4 wreg[NCOL][4];
  #pragma unroll
  for (int cc = 0; cc < NCOL; ++cc)
    #pragma unroll
    for (int q = 0; q < 4; ++q)
      wreg[cc][q] = *(const float4*)&W1[(size_t)(c0 + cc) * 2048 + 1024 + lane * 16 + q * 4];
  __syncthreads();
  float4* gp = gPan + (size_t)wb * NN;   // block-private g panel (fp32)
  const float* invA = (const float*)&meta[MI_INV];

  for (int l = 0; l < nL; ++l) {
    const int lo = s_lo[l];
    const int nA = s_nl[l];   // live rows (live-first ordering)

    // ---- A-phase: thread-per-row, own 4 columns; pack to bf16, 8B agent store ----
    for (int r = lo + tid; r < lo + nA; r += NT) {
      const int node = meta[MI_PERM + r];
      const int nd = meta[MI_DCNT + r];
      const float iv = invA[r];
      const int4 p0 = *(const int4*)&meta[MI_DPOS + r * MD];
      const int4 p1 = *(const int4*)&meta[MI_DPOS + r * MD + 4];
      const int dps[8] = {p0.x, p0.y, p0.z, p0.w, p1.x, p1.y, p1.z, p1.w};
      float sx = 0.f, sy = 0.f, sz = 0.f, sw = 0.f;
      #pragma unroll
      for (int d = 0; d < MD; ++d) {
        float4 v = gp[dps[d]];
        sx += (d < nd) ? v.x : 0.f;
        sy += (d < nd) ? v.y : 0.f;
        sz += (d < nd) ? v.z : 0.f;
        sw += (d < nd) ? v.w : 0.f;
      }
      const float4 pq = (l > 0 && r == lo + tid) ? preLDS[tid]
                                                 : *(const float4*)&preQ[(size_t)node * DM + c0];
      const unsigned short h0 = f2bf(gelu_f(pq.x + sx * iv));
      const unsigned short h1 = f2bf(gelu_f(pq.y + sy * iv));
      const unsigned short h2 = f2bf(gelu_f(pq.z + sz * iv));
      const unsigned short h3 = f2bf(gelu_f(pq.w + sw * iv));
      const unsigned long long u = (unsigned long long)h0 | ((unsigned long long)h1 << 16)
                                 | ((unsigned long long)h2 << 32) | ((unsigned long long)h3 << 48);
      __hip_atomic_store((unsigned long long*)&hPb[(size_t)r * DM + c0], u,
                         __ATOMIC_RELAXED, __HIP_MEMORY_SCOPE_AGENT);
    }
    __syncthreads();   // drains vmcnt -> h stores MALL-visible
    if (tid == 0)
      __hip_atomic_store(&meta[MI_ARRIVE + wb], l + 1, __ATOMIC_RELAXED, __HIP_MEMORY_SCOPE_AGENT);
    // prefetch next level's preQ into LDS (overlaps barrier)
    if (l + 1 < nL && tid < s_nl[l + 1]) {
      const int node2 = meta[MI_PERM + s_lo[l + 1] + tid];
      preLDS[tid] = *(const float4*)&preQ[(size_t)node2 * DM + c0];
    }
    if (tid < 64) {
      for (;;) {
        int m = 1 << 30;
        #pragma unroll
        for (int u = 0; u < 4; ++u) {
          int v = __hip_atomic_load(&meta[MI_ARRIVE + tid * 4 + u], __ATOMIC_RELAXED, __HIP_MEMORY_SCOPE_AGENT);
          m = v < m ? v : m;
        }
        #pragma unroll
        for (int off = 1; off < 64; off <<= 1) {
          int o = __shfl_xor(m, off);
          m = o < m ? o : m;
        }
        if (m >= l + 1) break;
        __builtin_amdgcn_s_sleep(1);
      }
    }
    __syncthreads();

    // ---- B-phase: 4-row unrolled wave-per-row; h bf16, W from VGPRs ----
    for (int base = wave * UR; base < nA; base += NWAVE * UR) {
      const int cnt2 = nA - base;           // rows remaining (>=1)
      ushort8 hv[UR][2];
      #pragma unroll
      for (int u = 0; u < UR; ++u) {
        const int r = lo + base + ((u < cnt2) ? u : 0);
        const ushort8* h8 = (const ushort8*)&hPb[(size_t)r * DM];
        hv[u][0] = h8[lane * 2];
        hv[u][1] = h8[lane * 2 + 1];
      }
      float rr[UR][NCOL];
      #pragma unroll
      for (int u = 0; u < UR; ++u) {
        float hf[16];
        #pragma unroll
        for (int e = 0; e < 8; ++e) { hf[e] = bf2f(hv[u][0][e]); hf[8 + e] = bf2f(hv[u][1][e]); }
        #pragma unroll
        for (int cc = 0; cc < NCOL; ++cc) {
          float a = 0.f;
          #pragma unroll
          for (int q = 0; q < 4; ++q)
            a += hf[q * 4 + 0] * wreg[cc][q].x + hf[q * 4 + 1] * wreg[cc][q].y
               + hf[q * 4 + 2] * wreg[cc][q].z + hf[q * 4 + 3] * wreg[cc][q].w;
          rr[u][cc] = a;
        }
      }
      #pragma unroll
      for (int off = 1; off < 64; off <<= 1)
        #pragma unroll
        for (int u = 0; u < UR; ++u)
          #pragma unroll
          for (int cc = 0; cc < NCOL; ++cc)
            rr[u][cc] += __shfl_xor(rr[u][cc], off);
      if (lane == 0) {
        #pragma unroll
        for (int u = 0; u < UR; ++u)
          if (u < cnt2) gp[lo + base + u] = make_float4(rr[u][0], rr[u][1], rr[u][2], rr[u][3]);
      }
    }
    __syncthreads();   // g writes visible block-wide for next level's A
  }

  // ---- logits epilogue (block 0): out = W2 @ h[root] + b2 ----
  if (wb == 0) {
    float* red = (float*)preLDS;
    const int j = tid >> 3, kc = tid & 7;   // 64 classes x 8 partials
    const ushort8* h8 = (const ushort8*)&hPb[(size_t)rootRow * DM];
    const float* wr2 = W2 + (size_t)j * DM;
    float acc = 0.f;
    for (int k = kc * 128; k < kc * 128 + 128; k += 8) {
      ushort8 hv = h8[k >> 3];
      float4 wa = *(const float4*)&wr2[k];
      float4 wb4 = *(const float4*)&wr2[k + 4];
      acc += bf2f(hv[0]) * wa.x + bf2f(hv[1]) * wa.y + bf2f(hv[2]) * wa.z + bf2f(hv[3]) * wa.w
           + bf2f(hv[4]) * wb4.x + bf2f(hv[5]) * wb4.y + bf2f(hv[6]) * wb4.z + bf2f(hv[7]) * wb4.w;
    }
    red[tid] = acc;
    __syncthreads();
    if (kc == 0) {
      float s = 0.f;
      #pragma unroll
      for (int e = 0; e < 8; ++e) s += red[j * 8 + e];
      out[j] = s + b2[j];
    }
  }
}

extern "C" void kernel_launch(void* const* d_in, const int* in_sizes, int n_in,
                              void* d_out, int out_size, void* d_ws, size_t ws_size,
                              hipStream_t stream) {
  const float* Q        = (const float*)d_in[0];
  const float* W1       = (const float*)d_in[1];
  const float* b1       = (const float*)d_in[2];
  const float* W2       = (const float*)d_in[3];
  const float* b2       = (const float*)d_in[4];
  const int*   dep_idx  = (const int*)d_in[5];
  const int*   dep_mask = (const int*)d_in[6];

  char* ws = (char*)d_ws;
  float*          preQ = (float*)ws;                              // [0, 16MB)
  unsigned short* hPb  = (unsigned short*)(ws + (16ull << 20));   // [16, 24) bf16 h
  float4*         gPan = (float4*)(ws + (32ull << 20));           // [32, 48) block-private g
  int*            meta = (int*)(ws + (48ull << 20));
  float*          out  = (float*)d_out;

  k_fused<<<dim3(258), dim3(1024), 0, stream>>>(Q, W1, b1, dep_idx, dep_mask, meta, preQ);
  k_levels<<<dim3(NW), dim3(NT), 0, stream>>>(W1, preQ, hPb, gPan, meta, W2, b2, out);
}

// Round 18
// 481.126 us; speedup vs baseline: 1.0885x; 1.0885x over previous
//
#include <hip/hip_runtime.h>

#define NN 4096
#define DM 1024
#define MD 8
#define NW 256          // worker blocks = column slices
#define NCOL 4          // columns per block (NW*NCOL = DM)
#define NT 512          // threads per k_levels block
#define NWAVE (NT / 64)
#define UR 4            // B-phase row unroll per wave (UR=8 spills at NT=512 — R15)
#define MAXL 4097

// meta layout (int offsets within meta region of d_ws) — R8 layout
#define MI_NLEV 0
#define MI_ROOTPOS 1
#define MI_ARRIVE 8     // arrive[NW]
#define MI_LO 1024      // levelOffset[nL+1]
#define MI_NL 6144      // live count per level
#define MI_PERM 10240   // perm[4096] (row -> node)
#define MI_DCNT 14336   // dep count per permuted row
#define MI_INV 18432    // (float) 1/nd per permuted row
#define MI_DPOS 22528   // dpos[4096*8]: permuted dep rows (padded with 0)

typedef __attribute__((ext_vector_type(8))) short bf16x8;
typedef __attribute__((ext_vector_type(8))) unsigned short ushort8;
typedef __attribute__((ext_vector_type(4))) float f32x4;

__device__ __forceinline__ float gelu_f(float x) {
  return 0.5f * x * (1.0f + erff(x * 0.70710678118654752440f));
}
__device__ __forceinline__ unsigned short f2bf(float x) {   // RTNE
  unsigned int u = __builtin_bit_cast(unsigned int, x);
  u += 0x7FFFu + ((u >> 16) & 1u);
  return (unsigned short)(u >> 16);
}
__device__ __forceinline__ float bf2f(unsigned short v) {
  return __builtin_bit_cast(float, (unsigned int)v << 16);
}

// ---------------- Q -> bf16 (RTNE), grid-stride ----------------
__global__ __launch_bounds__(1024) void k_cvt(
    const float* __restrict__ Q, unsigned short* __restrict__ Qb) {
  const int t = threadIdx.x;
  const size_t total = (size_t)NN * DM / 8;
  for (size_t c = (size_t)blockIdx.x * 1024 + t; c < total; c += 255 * 1024) {
    const size_t i = c * 8;
    float4 a = *(const float4*)&Q[i];
    float4 b = *(const float4*)&Q[i + 4];
    ushort8 o;
    o[0] = f2bf(a.x); o[1] = f2bf(a.y); o[2] = f2bf(a.z); o[3] = f2bf(a.w);
    o[4] = f2bf(b.x); o[5] = f2bf(b.y); o[6] = f2bf(b.z); o[7] = f2bf(b.w);
    *(ushort8*)&Qb[i] = o;
  }
}

// ---------------- fused: block 0 = graph prologue (1-barrier ballot GS);
// ---------------- blocks 1..256 = preQ MFMA tiles (threads 0..255) ----------------
__global__ __launch_bounds__(1024) void k_fused(
    const unsigned short* __restrict__ Qb, const float* __restrict__ W1,
    const float* __restrict__ b1, const int* __restrict__ dep_idx,
    const int* __restrict__ dep_mask, int* __restrict__ meta,
    float* __restrict__ preQ) {
  __shared__ int lvl[NN];     // 16KB
  __shared__ int liv[NN];     // 16KB
  __shared__ int cnt[2 * NN]; // 32KB
  __shared__ int pos[NN];     // 16KB
  __shared__ int wflag[2][16];
  __shared__ int s_max;
  const int t = threadIdx.x;

  if (blockIdx.x != 0) {
    // ---- preq tile (tile = (bid>>3, bid&7)) ----
    if (t >= 256) return;
    const int bid = blockIdx.x - 1;
    const int wave = t >> 6, lane = t & 63;
    const int wm = wave >> 1, wn = wave & 1;
    const int m0 = (bid >> 3) * 128 + wm * 64;
    const int n0 = (bid & 7) * 128 + wn * 64;
    const int lrow = lane & 15;           // A/B row within 16
    const int klo = (lane >> 4) * 8;      // k sub-chunk
    f32x4 acc[4][4] = {};
    for (int k0 = 0; k0 < DM; k0 += 32) {
      bf16x8 af[4];
      #pragma unroll
      for (int f = 0; f < 4; ++f)
        af[f] = *(const bf16x8*)&Qb[(size_t)(m0 + f * 16 + lrow) * DM + k0 + klo];
      bf16x8 bfr[4];
      #pragma unroll
      for (int g = 0; g < 4; ++g) {
        const float* wsrc = &W1[(size_t)(n0 + g * 16 + lrow) * 2048 + k0 + klo];
        float4 w0 = *(const float4*)&wsrc[0];
        float4 w1 = *(const float4*)&wsrc[4];
        bf16x8 bb;
        bb[0] = (short)f2bf(w0.x); bb[1] = (short)f2bf(w0.y);
        bb[2] = (short)f2bf(w0.z); bb[3] = (short)f2bf(w0.w);
        bb[4] = (short)f2bf(w1.x); bb[5] = (short)f2bf(w1.y);
        bb[6] = (short)f2bf(w1.z); bb[7] = (short)f2bf(w1.w);
        bfr[g] = bb;
      }
      #pragma unroll
      for (int f = 0; f < 4; ++f)
        #pragma unroll
        for (int g = 0; g < 4; ++g)
          acc[f][g] = __builtin_amdgcn_mfma_f32_16x16x32_bf16(af[f], bfr[g], acc[f][g], 0, 0, 0);
    }
    float b1v[4];
    #pragma unroll
    for (int g = 0; g < 4; ++g) b1v[g] = b1[n0 + g * 16 + lrow];
    const int mrow = (lane >> 4) * 4;
    #pragma unroll
    for (int f = 0; f < 4; ++f)
      #pragma unroll
      for (int g = 0; g < 4; ++g) {
        const int n = n0 + g * 16 + lrow;
        #pragma unroll
        for (int r = 0; r < 4; ++r)
          preQ[(size_t)(m0 + f * 16 + mrow + r) * DM + n] = acc[f][g][r] + b1v[g];
      }
    return;
  }

  // ---- prologue (1024 threads, single-barrier ballot convergence) ----
  for (int i = t; i < NN; i += 1024) { lvl[i] = 0; liv[i] = (i == NN - 1) ? 1 : 0; }
  for (int i = t; i < 2 * NN; i += 1024) cnt[i] = 0;
  if (t == 0) s_max = 0;
  __syncthreads();

  const int wid = t >> 6;
  int par = 0;

  // forward longest-path levels: 4 chunks of 1024 in index order
  for (int u = 0; u < 4; ++u) {
    const int i = u * 1024 + t;
    const int4 d0 = *(const int4*)&dep_idx[i * MD];
    const int4 d1 = *(const int4*)&dep_idx[i * MD + 4];
    const int4 m0 = *(const int4*)&dep_mask[i * MD];
    const int4 m1 = *(const int4*)&dep_mask[i * MD + 4];
    int my = 0;
    for (;;) {
      int m = 0;
      if (m0.x) { int l = lvl[d0.x] + 1; m = m > l ? m : l; }
      if (m0.y) { int l = lvl[d0.y] + 1; m = m > l ? m : l; }
      if (m0.z) { int l = lvl[d0.z] + 1; m = m > l ? m : l; }
      if (m0.w) { int l = lvl[d0.w] + 1; m = m > l ? m : l; }
      if (m1.x) { int l = lvl[d1.x] + 1; m = m > l ? m : l; }
      if (m1.y) { int l = lvl[d1.y] + 1; m = m > l ? m : l; }
      if (m1.z) { int l = lvl[d1.z] + 1; m = m > l ? m : l; }
      if (m1.w) { int l = lvl[d1.w] + 1; m = m > l ? m : l; }
      bool ch = false;
      if (m > my) { my = m; lvl[i] = m; ch = true; }
      const bool anyw = (__ballot(ch) != 0);
      if ((t & 63) == 0) wflag[par][wid] = anyw ? 1 : 0;
      __syncthreads();
      int any = 0;
      #pragma unroll
      for (int w = 0; w < 16; ++w) any |= wflag[par][w];
      par ^= 1;
      if (!any) break;
    }
  }
  // backward transitive liveness from root (reverse chunks)
  for (int u = 3; u >= 0; --u) {
    const int i = u * 1024 + t;
    const int4 d0 = *(const int4*)&dep_idx[i * MD];
    const int4 d1 = *(const int4*)&dep_idx[i * MD + 4];
    const int4 m0 = *(const int4*)&dep_mask[i * MD];
    const int4 m1 = *(const int4*)&dep_mask[i * MD + 4];
    for (;;) {
      bool ch = false;
      if (liv[i]) {
        if (m0.x && !liv[d0.x]) { liv[d0.x] = 1; ch = true; }
        if (m0.y && !liv[d0.y]) { liv[d0.y] = 1; ch = true; }
        if (m0.z && !liv[d0.z]) { liv[d0.z] = 1; ch = true; }
        if (m0.w && !liv[d0.w]) { liv[d0.w] = 1; ch = true; }
        if (m1.x && !liv[d1.x]) { liv[d1.x] = 1; ch = true; }
        if (m1.y && !liv[d1.y]) { liv[d1.y] = 1; ch = true; }
        if (m1.z && !liv[d1.z]) { liv[d1.z] = 1; ch = true; }
        if (m1.w && !liv[d1.w]) { liv[d1.w] = 1; ch = true; }
      }
      const bool anyw = (__ballot(ch) != 0);
      if ((t & 63) == 0) wflag[par][wid] = anyw ? 1 : 0;
      __syncthreads();
      int any = 0;
      #pragma unroll
      for (int w = 0; w < 16; ++w) any |= wflag[par][w];
      par ^= 1;
      if (!any) break;
    }
  }
  // counting sort by key = 2*level + (dead?1:0)
  for (int i = t; i < NN; i += 1024) {
    atomicAdd(&cnt[2 * lvl[i] + (liv[i] ? 0 : 1)], 1);
    atomicMax(&s_max, lvl[i]);
  }
  __syncthreads();
  const int nL = s_max + 1;
  if (t == 0) {
    int off = 0;
    for (int l = 0; l < nL; ++l) {
      meta[MI_LO + l] = off;
      meta[MI_NL + l] = cnt[2 * l];
      const int a = cnt[2 * l], b = cnt[2 * l + 1];
      cnt[2 * l] = off; off += a;
      cnt[2 * l + 1] = off; off += b;
    }
    meta[MI_LO + nL] = off;
    meta[MI_NLEV] = nL;
  }
  __syncthreads();
  for (int i = t; i < NN; i += 1024)
    pos[i] = atomicAdd(&cnt[2 * lvl[i] + (liv[i] ? 0 : 1)], 1);
  __syncthreads();
  for (int i = t; i < NN; i += 1024) {
    const int r = pos[i];
    meta[MI_PERM + r] = i;
    const int4 d0 = *(const int4*)&dep_idx[i * MD];
    const int4 d1 = *(const int4*)&dep_idx[i * MD + 4];
    const int4 m0 = *(const int4*)&dep_mask[i * MD];
    const int4 m1 = *(const int4*)&dep_mask[i * MD + 4];
    const int dd[8] = {d0.x, d0.y, d0.z, d0.w, d1.x, d1.y, d1.z, d1.w};
    const int mm[8] = {m0.x, m0.y, m0.z, m0.w, m1.x, m1.y, m1.z, m1.w};
    int nd = 0;
    #pragma unroll
    for (int k = 0; k < MD; ++k)
      if (mm[k]) { meta[MI_DPOS + r * MD + nd] = pos[dd[k]]; ++nd; }
    for (int k = nd; k < MD; ++k) meta[MI_DPOS + r * MD + k] = 0;
    meta[MI_DCNT + r] = nd;
    ((float*)meta)[MI_INV + r] = nd ? 1.0f / (float)nd : 0.0f;
  }
  if (t == 0) meta[MI_ROOTPOS] = pos[NN - 1];
  for (int i = t; i < NW; i += 1024) meta[MI_ARRIVE + i] = 0;
}

// ---------------- persistent column-sliced dataflow (bf16 h, W in VGPRs) + logits ----------------
__global__ __launch_bounds__(NT) void k_levels(
    const float* __restrict__ W1, const float* __restrict__ preQ,
    unsigned short* __restrict__ hPb, float4* __restrict__ gPan, int* __restrict__ meta,
    const float* __restrict__ W2, const float* __restrict__ b2, float* __restrict__ out) {
  const int tid = threadIdx.x;
  const int wb = blockIdx.x;
  const int c0 = wb * NCOL;
  const int wave = tid >> 6, lane = tid & 63;
  const int nL = meta[MI_NLEV];
  const int rootRow = meta[MI_ROOTPOS];
  __shared__ int s_lo[MAXL];
  __shared__ int s_nl[MAXL];
  __shared__ float4 preLDS[NT];
  for (int i = tid; i <= nL; i += NT) s_lo[i] = meta[MI_LO + i];
  for (int i = tid; i < nL; i += NT) s_nl[i] = meta[MI_NL + i];
  // W1c slice (4 cols x 1024 k) fp32 in registers; lane's k-window = lane*16..+15
  float4 wreg[NCOL][4];
  #pragma unroll
  for (int cc = 0; cc < NCOL; ++cc)
    #pragma unroll
    for (int q = 0; q < 4; ++q)
      wreg[cc][q] = *(const float4*)&W1[(size_t)(c0 + cc) * 2048 + 1024 + lane * 16 + q * 4];
  __syncthreads();
  float4* gp = gPan + (size_t)wb * NN;   // block-private g panel (fp32)
  const float* invA = (const float*)&meta[MI_INV];

  for (int l = 0; l < nL; ++l) {
    const int lo = s_lo[l];
    const int nA = s_nl[l];   // live rows (live-first ordering)

    // ---- A-phase: thread-per-row, own 4 columns; pack to bf16, 8B agent store ----
    for (int r = lo + tid; r < lo + nA; r += NT) {
      const int node = meta[MI_PERM + r];
      const int nd = meta[MI_DCNT + r];
      const float iv = invA[r];
      const int4 p0 = *(const int4*)&meta[MI_DPOS + r * MD];
      const int4 p1 = *(const int4*)&meta[MI_DPOS + r * MD + 4];
      const int dps[8] = {p0.x, p0.y, p0.z, p0.w, p1.x, p1.y, p1.z, p1.w};
      float sx = 0.f, sy = 0.f, sz = 0.f, sw = 0.f;
      #pragma unroll
      for (int d = 0; d < MD; ++d) {
        float4 v = gp[dps[d]];
        sx += (d < nd) ? v.x : 0.f;
        sy += (d < nd) ? v.y : 0.f;
        sz += (d < nd) ? v.z : 0.f;
        sw += (d < nd) ? v.w : 0.f;
      }
      const float4 pq = (l > 0 && r == lo + tid) ? preLDS[tid]
                                                 : *(const float4*)&preQ[(size_t)node * DM + c0];
      const unsigned short h0 = f2bf(gelu_f(pq.x + sx * iv));
      const unsigned short h1 = f2bf(gelu_f(pq.y + sy * iv));
      const unsigned short h2 = f2bf(gelu_f(pq.z + sz * iv));
      const unsigned short h3 = f2bf(gelu_f(pq.w + sw * iv));
      const unsigned long long u = (unsigned long long)h0 | ((unsigned long long)h1 << 16)
                                 | ((unsigned long long)h2 << 32) | ((unsigned long long)h3 << 48);
      __hip_atomic_store((unsigned long long*)&hPb[(size_t)r * DM + c0], u,
                         __ATOMIC_RELAXED, __HIP_MEMORY_SCOPE_AGENT);
    }
    __syncthreads();   // drains vmcnt -> h stores MALL-visible
    if (tid == 0)
      __hip_atomic_store(&meta[MI_ARRIVE + wb], l + 1, __ATOMIC_RELAXED, __HIP_MEMORY_SCOPE_AGENT);
    // prefetch next level's preQ into LDS (overlaps barrier)
    if (l + 1 < nL && tid < s_nl[l + 1]) {
      const int node2 = meta[MI_PERM + s_lo[l + 1] + tid];
      preLDS[tid] = *(const float4*)&preQ[(size_t)node2 * DM + c0];
    }
    if (tid < 64) {
      for (;;) {
        int m = 1 << 30;
        #pragma unroll
        for (int u = 0; u < 4; ++u) {
          int v = __hip_atomic_load(&meta[MI_ARRIVE + tid * 4 + u], __ATOMIC_RELAXED, __HIP_MEMORY_SCOPE_AGENT);
          m = v < m ? v : m;
        }
        #pragma unroll
        for (int off = 1; off < 64; off <<= 1) {
          int o = __shfl_xor(m, off);
          m = o < m ? o : m;
        }
        if (m >= l + 1) break;
        __builtin_amdgcn_s_sleep(1);
      }
    }
    __syncthreads();

    // ---- B-phase: 4-row unrolled wave-per-row; h bf16, W from VGPRs ----
    for (int base = wave * UR; base < nA; base += NWAVE * UR) {
      const int cnt = nA - base;            // rows remaining (>=1)
      ushort8 hv[UR][2];
      #pragma unroll
      for (int u = 0; u < UR; ++u) {
        const int r = lo + base + ((u < cnt) ? u : 0);
        const ushort8* h8 = (const ushort8*)&hPb[(size_t)r * DM];
        hv[u][0] = h8[lane * 2];
        hv[u][1] = h8[lane * 2 + 1];
      }
      float rr[UR][NCOL];
      #pragma unroll
      for (int u = 0; u < UR; ++u) {
        float hf[16];
        #pragma unroll
        for (int e = 0; e < 8; ++e) { hf[e] = bf2f(hv[u][0][e]); hf[8 + e] = bf2f(hv[u][1][e]); }
        #pragma unroll
        for (int cc = 0; cc < NCOL; ++cc) {
          float a = 0.f;
          #pragma unroll
          for (int q = 0; q < 4; ++q)
            a += hf[q * 4 + 0] * wreg[cc][q].x + hf[q * 4 + 1] * wreg[cc][q].y
               + hf[q * 4 + 2] * wreg[cc][q].z + hf[q * 4 + 3] * wreg[cc][q].w;
          rr[u][cc] = a;
        }
      }
      #pragma unroll
      for (int off = 1; off < 64; off <<= 1)
        #pragma unroll
        for (int u = 0; u < UR; ++u)
          #pragma unroll
          for (int cc = 0; cc < NCOL; ++cc)
            rr[u][cc] += __shfl_xor(rr[u][cc], off);
      if (lane == 0) {
        #pragma unroll
        for (int u = 0; u < UR; ++u)
          if (u < cnt) gp[lo + base + u] = make_float4(rr[u][0], rr[u][1], rr[u][2], rr[u][3]);
      }
    }
    __syncthreads();   // g writes visible block-wide for next level's A
  }

  // ---- logits epilogue (block 0): out = W2 @ h[root] + b2 ----
  if (wb == 0) {
    float* red = (float*)preLDS;
    const int j = tid >> 3, kc = tid & 7;   // 64 classes x 8 partials
    const ushort8* h8 = (const ushort8*)&hPb[(size_t)rootRow * DM];
    const float* wr2 = W2 + (size_t)j * DM;
    float acc = 0.f;
    for (int k = kc * 128; k < kc * 128 + 128; k += 8) {
      ushort8 hv = h8[k >> 3];
      float4 wa = *(const float4*)&wr2[k];
      float4 wb4 = *(const float4*)&wr2[k + 4];
      acc += bf2f(hv[0]) * wa.x + bf2f(hv[1]) * wa.y + bf2f(hv[2]) * wa.z + bf2f(hv[3]) * wa.w
           + bf2f(hv[4]) * wb4.x + bf2f(hv[5]) * wb4.y + bf2f(hv[6]) * wb4.z + bf2f(hv[7]) * wb4.w;
    }
    red[tid] = acc;
    __syncthreads();
    if (kc == 0) {
      float s = 0.f;
      #pragma unroll
      for (int e = 0; e < 8; ++e) s += red[j * 8 + e];
      out[j] = s + b2[j];
    }
  }
}

extern "C" void kernel_launch(void* const* d_in, const int* in_sizes, int n_in,
                              void* d_out, int out_size, void* d_ws, size_t ws_size,
                              hipStream_t stream) {
  const float* Q        = (const float*)d_in[0];
  const float* W1       = (const float*)d_in[1];
  const float* b1       = (const float*)d_in[2];
  const float* W2       = (const float*)d_in[3];
  const float* b2       = (const float*)d_in[4];
  const int*   dep_idx  = (const int*)d_in[5];
  const int*   dep_mask = (const int*)d_in[6];

  char* ws = (char*)d_ws;
  float*          preQ = (float*)ws;                              // [0, 16MB)
  unsigned short* hPb  = (unsigned short*)(ws + (16ull << 20));   // [16, 24) bf16 h
  unsigned short* Qb   = (unsigned short*)(ws + (24ull << 20));   // [24, 32) bf16 Q
  float4*         gPan = (float4*)(ws + (32ull << 20));           // [32, 48) block-private g
  int*            meta = (int*)(ws + (48ull << 20));
  float*          out  = (float*)d_out;

  k_cvt<<<dim3(255), dim3(1024), 0, stream>>>(Q, Qb);
  k_fused<<<dim3(257), dim3(1024), 0, stream>>>(Qb, W1, b1, dep_idx, dep_mask, meta, preQ);
  k_levels<<<dim3(NW), dim3(NT), 0, stream>>>(W1, preQ, hPb, gPan, meta, W2, b2, out);
}